// Round 3
// baseline (94.795 us; speedup 1.0000x reference)
//
#include <hip/hip_runtime.h>
#include <climits>

#define A_N 33600
#define G_N 256
#define NC 80
#define KK 10
#define CAP 2048          // max inside-anchors per gt: worst box 128x128 -> ~1344 expected, +19 sigma
#define NLOAD 8           // CAP / 256

// Monotone float->uint mapping: preserves total order (incl. +/-inf).
__device__ __forceinline__ unsigned int ford(float f) {
    unsigned int u = __float_as_uint(f);
    return (u & 0x80000000u) ? ~u : (u | 0x80000000u);
}

__device__ __forceinline__ unsigned long long umin64(unsigned long long a, unsigned long long b) {
    return a < b ? a : b;
}

// Anchor-parallel: fused per-anchor logsum + sparse (inside & iou>0) cost emission
// into per-gt buckets. inside == in_gt exactly (RADIUS=2.5 makes the center test
// redundant: cx-rx <= x1 - ~2w, slack >= 16px >> fp rounding).
__global__ __launch_bounds__(64) void k_pairs(
    const float* __restrict__ scores, const float* __restrict__ pred_b,
    const float* __restrict__ anchors, const int* __restrict__ gt_labels,
    const float* __restrict__ gt_b,
    unsigned long long* __restrict__ bucket, int* __restrict__ cnt)
{
    __shared__ float4 gbox[G_N];
    __shared__ int glab[G_N];
    int tid = threadIdx.x;
    for (int i = tid; i < G_N; i += 64) {
        gbox[i] = reinterpret_cast<const float4*>(gt_b)[i];
        glab[i] = gt_labels[i];
    }
    __syncthreads();

    int a = blockIdx.x * 64 + tid;
    if (a >= A_N) return;

    float4 pb = reinterpret_cast<const float4*>(pred_b)[a];
    float2 ap = reinterpret_cast<const float2*>(anchors)[a];
    float area_p = (pb.z - pb.x) * (pb.w - pb.y);

    // logsum[a] = sum_c log_sigmoid(-s[a,c]) = -sum_c (max(s,0) + log1p(exp(-|s|)))
    const float4* row = reinterpret_cast<const float4*>(scores + (long)a * NC);
    float ls = 0.f;
    #pragma unroll
    for (int i = 0; i < NC / 4; i++) {
        float4 v = row[i];
        ls -= fmaxf(v.x, 0.f) + log1pf(expf(-fabsf(v.x)));
        ls -= fmaxf(v.y, 0.f) + log1pf(expf(-fabsf(v.y)));
        ls -= fmaxf(v.z, 0.f) + log1pf(expf(-fabsf(v.z)));
        ls -= fmaxf(v.w, 0.f) + log1pf(expf(-fabsf(v.w)));
    }

    #pragma unroll 4
    for (int g = 0; g < G_N; g++) {
        float4 gb = gbox[g];   // LDS broadcast
        bool in_gt = (ap.x >= gb.x) & (ap.x <= gb.z) & (ap.y >= gb.y) & (ap.y <= gb.w);
        if (!in_gt) continue;

        float ltx = fmaxf(gb.x, pb.x), lty = fmaxf(gb.y, pb.y);
        float rbx = fminf(gb.z, pb.z), rby = fminf(gb.w, pb.w);
        float w = fmaxf(rbx - ltx, 0.f), h = fmaxf(rby - lty, 0.f);
        float overlap = w * h;
        if (!(overlap > 0.f)) continue;   // inside & iou==0 -> +inf cost, never selected

        float area_g = (gb.z - gb.x) * (gb.w - gb.y);
        float uni = area_g + area_p - overlap + 1e-6f;
        float iou = overlap / uni;
        float s = scores[(long)a * NC + glab[g]];
        // log_sigmoid(s)-log_sigmoid(-s) == s (shared log1p term cancels)
        float cost = (-s - ls) + 3.0f * (-logf(iou));
        unsigned long long key = ((unsigned long long)ford(cost) << 32) | (unsigned int)a;

        int slot = atomicAdd(&cnt[g], 1);
        if (slot < CAP) bucket[(size_t)g * CAP + slot] = key;
    }
}

// One block per gt: select min(cnt,10) smallest keys (exact, order-independent),
// scatter atomicMax into assigned. cnt==0: ks=1, winner = lowest-index anchor
// with iou>0 (cost exactly 1e10 beats all +inf), else anchor 0.
__global__ __launch_bounds__(256) void k_select(
    const unsigned long long* __restrict__ bucket, const int* __restrict__ cnt_arr,
    const float* __restrict__ pred_b, const float* __restrict__ gt_b,
    int* __restrict__ assigned)
{
    int g = blockIdx.x, tid = threadIdx.x;
    int wid = tid >> 6, lane = tid & 63;
    __shared__ unsigned long long swin[4];
    __shared__ unsigned long long sel[KK];
    __shared__ int smin[4];

    int cnt = cnt_arr[g];

    if (cnt == 0) {   // rare fallback: first anchor whose pred box overlaps gt
        float4 gb = reinterpret_cast<const float4*>(gt_b)[g];
        int best = INT_MAX;
        for (int a = tid; a < A_N; a += 256) {
            float4 pb = reinterpret_cast<const float4*>(pred_b)[a];
            float w = fminf(gb.z, pb.z) - fmaxf(gb.x, pb.x);
            float h = fminf(gb.w, pb.w) - fmaxf(gb.y, pb.y);
            if (w > 0.f && h > 0.f && a < best) best = a;
        }
        #pragma unroll
        for (int off = 32; off; off >>= 1) best = min(best, __shfl_down(best, off));
        if (lane == 0) smin[wid] = best;
        __syncthreads();
        if (tid == 0) {
            int m = min(min(smin[0], smin[1]), min(smin[2], smin[3]));
            if (m == INT_MAX) m = 0;
            atomicMax(&assigned[m], g);
        }
        return;
    }

    int k = cnt < KK ? cnt : KK;
    int nreal = cnt < CAP ? cnt : CAP;
    const unsigned long long* bk = bucket + (size_t)g * CAP;
    unsigned long long kv[NLOAD];
    #pragma unroll
    for (int i = 0; i < NLOAD; i++) {
        int idx = tid + i * 256;
        kv[i] = (idx < nreal) ? bk[idx] : ~0ull;
    }

    for (int it = 0; it < k; it++) {
        unsigned long long m = kv[0];
        #pragma unroll
        for (int i = 1; i < NLOAD; i++) m = umin64(m, kv[i]);
        #pragma unroll
        for (int off = 32; off; off >>= 1) m = umin64(m, __shfl_down(m, off));
        if (lane == 0) swin[wid] = m;
        __syncthreads();
        if (tid == 0)
            sel[it] = umin64(umin64(swin[0], swin[1]), umin64(swin[2], swin[3]));
        __syncthreads();
        unsigned long long win = sel[it];
        #pragma unroll
        for (int i = 0; i < NLOAD; i++) if (kv[i] == win) kv[i] = ~0ull;  // unique key
    }

    if (tid < k) atomicMax(&assigned[(int)(sel[tid] & 0xffffffffu)], g);
}

__global__ void k_out(const int* __restrict__ assigned, const int* __restrict__ gt_labels,
                      const float* __restrict__ gt_b, const float* __restrict__ pred_b,
                      float* __restrict__ out_labels, float* __restrict__ out_bbox,
                      float* __restrict__ out_scores) {
    int a = blockIdx.x * blockDim.x + threadIdx.x;
    if (a >= A_N) return;
    int g = assigned[a];
    bool pos = g >= 0;
    int label = NC;
    float4 ob = make_float4(0.f, 0.f, 0.f, 0.f);
    float val = 0.f;
    if (pos) {
        label = gt_labels[g];
        float x1 = gt_b[g*4+0], y1 = gt_b[g*4+1], x2 = gt_b[g*4+2], y2 = gt_b[g*4+3];
        ob = make_float4(x1, y1, x2, y2);
        float4 pb = reinterpret_cast<const float4*>(pred_b)[a];
        float ltx = fmaxf(x1, pb.x), lty = fmaxf(y1, pb.y);
        float rbx = fminf(x2, pb.z), rby = fminf(y2, pb.w);
        float w = fmaxf(rbx-ltx, 0.f), h = fmaxf(rby-lty, 0.f);
        float overlap = w*h;
        float area_g = (x2-x1)*(y2-y1);
        float area_p = (pb.z-pb.x)*(pb.w-pb.y);
        float uni = area_g + area_p - overlap + 1e-6f;
        val = overlap/uni;
    }
    out_labels[a] = (float)label;
    reinterpret_cast<float4*>(out_bbox)[a] = ob;
    out_scores[(long)a*(NC+1) + label] = val;
}

extern "C" void kernel_launch(void* const* d_in, const int* in_sizes, int n_in,
                              void* d_out, int out_size, void* d_ws, size_t ws_size,
                              hipStream_t stream) {
    const float* pred_scores   = (const float*)d_in[0];
    const float* pred_bboxes   = (const float*)d_in[1];
    const float* anchor_points = (const float*)d_in[2];
    const int*   gt_labels     = (const int*)d_in[3];
    const float* gt_bboxes     = (const float*)d_in[4];

    char* ws = (char*)d_ws;
    unsigned long long* bucket = (unsigned long long*)ws;              // G*CAP u64 (8B-aligned first)
    size_t bucket_bytes = (size_t)G_N * CAP * 8;                       // 4 MiB
    int* assigned = (int*)(ws + bucket_bytes);                         // A ints
    int* cnt      = (int*)(ws + bucket_bytes + (size_t)A_N * 4);       // G ints

    float* out_labels = (float*)d_out;          // A
    float* out_bbox   = out_labels + A_N;       // A*4
    float* out_scores = out_bbox + 4*A_N;       // A*81

    hipMemsetAsync(cnt, 0, (size_t)G_N * sizeof(int), stream);
    hipMemsetAsync(assigned, 0xFF, (size_t)A_N * sizeof(int), stream);          // -1
    hipMemsetAsync(out_scores, 0, (size_t)A_N * (NC + 1) * sizeof(float), stream);

    k_pairs<<<(A_N + 63) / 64, 64, 0, stream>>>(pred_scores, pred_bboxes, anchor_points,
                                                gt_labels, gt_bboxes, bucket, cnt);
    k_select<<<G_N, 256, 0, stream>>>(bucket, cnt, pred_bboxes, gt_bboxes, assigned);
    k_out<<<(A_N + 255) / 256, 256, 0, stream>>>(assigned, gt_labels, gt_bboxes,
                                                 pred_bboxes, out_labels, out_bbox, out_scores);
}

// Round 4
// 60.003 us; speedup vs baseline: 1.5799x; 1.5799x over previous
//
#include <hip/hip_runtime.h>
#include <climits>

#define A_N 33600
#define G_N 256
#define NC 80
#define KK 10
#define CAP 2048          // max inside-anchors per gt: worst box 128x128 -> ~1344 expected, +19 sigma
#define NLOAD 8           // CAP / 256
#define GCHUNK 32
#define NCHUNK (G_N / GCHUNK)   // 8

// Monotone float->uint mapping: preserves total order (incl. +/-inf).
__device__ __forceinline__ unsigned int ford(float f) {
    unsigned int u = __float_as_uint(f);
    return (u & 0x80000000u) ? ~u : (u | 0x80000000u);
}

__device__ __forceinline__ unsigned long long umin64(unsigned long long a, unsigned long long b) {
    return a < b ? a : b;
}

// Fused init: per-anchor logsum (one wave per anchor) + cnt=0 + assigned=-1 +
// out_scores zeroing. Replaces 3 hipMemsetAsync dispatches.
// Grid: 8400 blocks x 256 threads = 33600 waves (one per anchor).
__global__ __launch_bounds__(256) void k_init(
    const float* __restrict__ scores, float* __restrict__ logsum,
    int* __restrict__ cnt, int* __restrict__ assigned, float4* __restrict__ out_scores4)
{
    int t = blockIdx.x * 256 + threadIdx.x;
    int wv = t >> 6, lane = t & 63;

    if (t < G_N) cnt[t] = 0;
    if (t < A_N) assigned[t] = -1;
    if (t < (A_N * 81) / 4) out_scores4[t] = make_float4(0.f, 0.f, 0.f, 0.f);

    // logsum[a] = sum_c log_sigmoid(-s[a,c]) = -sum_c (max(s,0) + log1p(exp(-|s|)))
    const float* row = scores + (long)wv * NC;
    float acc = 0.f;
    for (int c = lane; c < NC; c += 64) {
        float s = row[c];
        acc -= (fmaxf(s, 0.f) + log1pf(expf(-fabsf(s))));
    }
    #pragma unroll
    for (int off = 32; off > 0; off >>= 1) acc += __shfl_down(acc, off);
    if (lane == 0) logsum[wv] = acc;
}

// Anchor-parallel sparse emission, gt-chunked for occupancy:
// grid (132 anchor-blocks, 8 gt-chunks) x 256 threads.
// inside == in_gt exactly (RADIUS=2.5 makes the center test redundant).
__global__ __launch_bounds__(256) void k_pairs(
    const float* __restrict__ scores, const float* __restrict__ pred_b,
    const float* __restrict__ anchors, const int* __restrict__ gt_labels,
    const float* __restrict__ gt_b, const float* __restrict__ logsum,
    unsigned long long* __restrict__ bucket, int* __restrict__ cnt)
{
    __shared__ float4 gbox[GCHUNK];
    __shared__ int glab[GCHUNK];
    int tid = threadIdx.x;
    int gc = blockIdx.y;
    if (tid < GCHUNK) {
        gbox[tid] = reinterpret_cast<const float4*>(gt_b)[gc * GCHUNK + tid];
        glab[tid] = gt_labels[gc * GCHUNK + tid];
    }
    __syncthreads();

    int a = blockIdx.x * 256 + tid;
    if (a >= A_N) return;

    float4 pb = reinterpret_cast<const float4*>(pred_b)[a];
    float2 ap = reinterpret_cast<const float2*>(anchors)[a];
    float area_p = (pb.z - pb.x) * (pb.w - pb.y);
    float ls = logsum[a];

    #pragma unroll 4
    for (int g = 0; g < GCHUNK; g++) {
        float4 gb = gbox[g];   // LDS broadcast
        bool in_gt = (ap.x >= gb.x) & (ap.x <= gb.z) & (ap.y >= gb.y) & (ap.y <= gb.w);
        if (!in_gt) continue;

        float ltx = fmaxf(gb.x, pb.x), lty = fmaxf(gb.y, pb.y);
        float rbx = fminf(gb.z, pb.z), rby = fminf(gb.w, pb.w);
        float w = fmaxf(rbx - ltx, 0.f), h = fmaxf(rby - lty, 0.f);
        float overlap = w * h;
        if (!(overlap > 0.f)) continue;   // inside & iou==0 -> +inf cost, never selected

        int gg = gc * GCHUNK + g;
        float area_g = (gb.z - gb.x) * (gb.w - gb.y);
        float uni = area_g + area_p - overlap + 1e-6f;
        float iou = overlap / uni;
        float s = scores[(long)a * NC + glab[g]];
        // log_sigmoid(s)-log_sigmoid(-s) == s (shared log1p term cancels)
        float cost = (-s - ls) + 3.0f * (-logf(iou));
        unsigned long long key = ((unsigned long long)ford(cost) << 32) | (unsigned int)a;

        int slot = atomicAdd(&cnt[gg], 1);
        if (slot < CAP) bucket[(size_t)gg * CAP + slot] = key;
    }
}

// One block per gt: select min(cnt,10) smallest keys (exact, order-independent),
// scatter atomicMax into assigned. cnt==0: ks=1, winner = lowest-index anchor
// with iou>0 (cost exactly 1e10 beats all +inf), else anchor 0.
__global__ __launch_bounds__(256) void k_select(
    const unsigned long long* __restrict__ bucket, const int* __restrict__ cnt_arr,
    const float* __restrict__ pred_b, const float* __restrict__ gt_b,
    int* __restrict__ assigned)
{
    int g = blockIdx.x, tid = threadIdx.x;
    int wid = tid >> 6, lane = tid & 63;
    __shared__ unsigned long long swin[4];
    __shared__ unsigned long long sel[KK];
    __shared__ int smin[4];

    int cnt = cnt_arr[g];

    if (cnt == 0) {   // rare fallback: first anchor whose pred box overlaps gt
        float4 gb = reinterpret_cast<const float4*>(gt_b)[g];
        int best = INT_MAX;
        for (int a = tid; a < A_N; a += 256) {
            float4 pb = reinterpret_cast<const float4*>(pred_b)[a];
            float w = fminf(gb.z, pb.z) - fmaxf(gb.x, pb.x);
            float h = fminf(gb.w, pb.w) - fmaxf(gb.y, pb.y);
            if (w > 0.f && h > 0.f && a < best) best = a;
        }
        #pragma unroll
        for (int off = 32; off; off >>= 1) best = min(best, __shfl_down(best, off));
        if (lane == 0) smin[wid] = best;
        __syncthreads();
        if (tid == 0) {
            int m = min(min(smin[0], smin[1]), min(smin[2], smin[3]));
            if (m == INT_MAX) m = 0;
            atomicMax(&assigned[m], g);
        }
        return;
    }

    int k = cnt < KK ? cnt : KK;
    int nreal = cnt < CAP ? cnt : CAP;
    const unsigned long long* bk = bucket + (size_t)g * CAP;
    unsigned long long kv[NLOAD];
    #pragma unroll
    for (int i = 0; i < NLOAD; i++) {
        int idx = tid + i * 256;
        kv[i] = (idx < nreal) ? bk[idx] : ~0ull;
    }

    for (int it = 0; it < k; it++) {
        unsigned long long m = kv[0];
        #pragma unroll
        for (int i = 1; i < NLOAD; i++) m = umin64(m, kv[i]);
        #pragma unroll
        for (int off = 32; off; off >>= 1) m = umin64(m, __shfl_down(m, off));
        if (lane == 0) swin[wid] = m;
        __syncthreads();
        if (tid == 0)
            sel[it] = umin64(umin64(swin[0], swin[1]), umin64(swin[2], swin[3]));
        __syncthreads();
        unsigned long long win = sel[it];
        #pragma unroll
        for (int i = 0; i < NLOAD; i++) if (kv[i] == win) kv[i] = ~0ull;  // unique key
    }

    if (tid < k) atomicMax(&assigned[(int)(sel[tid] & 0xffffffffu)], g);
}

__global__ void k_out(const int* __restrict__ assigned, const int* __restrict__ gt_labels,
                      const float* __restrict__ gt_b, const float* __restrict__ pred_b,
                      float* __restrict__ out_labels, float* __restrict__ out_bbox,
                      float* __restrict__ out_scores) {
    int a = blockIdx.x * blockDim.x + threadIdx.x;
    if (a >= A_N) return;
    int g = assigned[a];
    bool pos = g >= 0;
    int label = NC;
    float4 ob = make_float4(0.f, 0.f, 0.f, 0.f);
    float val = 0.f;
    if (pos) {
        label = gt_labels[g];
        float x1 = gt_b[g*4+0], y1 = gt_b[g*4+1], x2 = gt_b[g*4+2], y2 = gt_b[g*4+3];
        ob = make_float4(x1, y1, x2, y2);
        float4 pb = reinterpret_cast<const float4*>(pred_b)[a];
        float ltx = fmaxf(x1, pb.x), lty = fmaxf(y1, pb.y);
        float rbx = fminf(x2, pb.z), rby = fminf(y2, pb.w);
        float w = fmaxf(rbx-ltx, 0.f), h = fmaxf(rby-lty, 0.f);
        float overlap = w*h;
        float area_g = (x2-x1)*(y2-y1);
        float area_p = (pb.z-pb.x)*(pb.w-pb.y);
        float uni = area_g + area_p - overlap + 1e-6f;
        val = overlap/uni;
    }
    out_labels[a] = (float)label;
    reinterpret_cast<float4*>(out_bbox)[a] = ob;
    out_scores[(long)a*(NC+1) + label] = val;
}

extern "C" void kernel_launch(void* const* d_in, const int* in_sizes, int n_in,
                              void* d_out, int out_size, void* d_ws, size_t ws_size,
                              hipStream_t stream) {
    const float* pred_scores   = (const float*)d_in[0];
    const float* pred_bboxes   = (const float*)d_in[1];
    const float* anchor_points = (const float*)d_in[2];
    const int*   gt_labels     = (const int*)d_in[3];
    const float* gt_bboxes     = (const float*)d_in[4];

    char* ws = (char*)d_ws;
    unsigned long long* bucket = (unsigned long long*)ws;              // G*CAP u64 (8B-aligned first)
    size_t bucket_bytes = (size_t)G_N * CAP * 8;                       // 4 MiB
    int*   assigned = (int*)(ws + bucket_bytes);                       // A ints
    int*   cnt      = (int*)(ws + bucket_bytes + (size_t)A_N * 4);     // G ints
    float* logsum   = (float*)(ws + bucket_bytes + (size_t)A_N * 4 + G_N * 4); // A floats

    float* out_labels = (float*)d_out;          // A
    float* out_bbox   = out_labels + A_N;       // A*4
    float* out_scores = out_bbox + 4*A_N;       // A*81 (offset 672000 B, 16B-aligned)

    k_init<<<A_N / 4, 256, 0, stream>>>(pred_scores, logsum, cnt, assigned,
                                        (float4*)out_scores);
    dim3 pg((A_N + 255) / 256, NCHUNK);
    k_pairs<<<pg, 256, 0, stream>>>(pred_scores, pred_bboxes, anchor_points,
                                    gt_labels, gt_bboxes, logsum, bucket, cnt);
    k_select<<<G_N, 256, 0, stream>>>(bucket, cnt, pred_bboxes, gt_bboxes, assigned);
    k_out<<<(A_N + 255) / 256, 256, 0, stream>>>(assigned, gt_labels, gt_bboxes,
                                                 pred_bboxes, out_labels, out_bbox, out_scores);
}

// Round 5
// 45.419 us; speedup vs baseline: 2.0871x; 1.3211x over previous
//
#include <hip/hip_runtime.h>
#include <climits>

#define A_N 33600
#define G_N 256
#define NC 80
#define KK 10
#define CAP 2048          // max candidates per gt (worst-case headroom)
#define NLOAD 8           // CAP / 256
#define GCHUNK 32
#define NCHUNK (G_N / GCHUNK)   // 8
#define FBSEG 16
#define FBSEG_LEN (A_N / FBSEG) // 2100

// Monotone float->uint mapping: preserves total order (incl. +/-inf).
__device__ __forceinline__ unsigned int ford(float f) {
    unsigned int u = __float_as_uint(f);
    return (u & 0x80000000u) ? ~u : (u | 0x80000000u);
}

__device__ __forceinline__ unsigned long long umin64(unsigned long long a, unsigned long long b) {
    return a < b ? a : b;
}

// Fused init: per-anchor logsum (one wave per anchor) + cnt=0 + fb=INT_MAX +
// assigned=-1 + out_scores zeroing. Replaces 3 hipMemsetAsync dispatches.
__global__ __launch_bounds__(256) void k_init(
    const float* __restrict__ scores, float* __restrict__ logsum,
    int* __restrict__ cnt, int* __restrict__ fb,
    int* __restrict__ assigned, float4* __restrict__ out_scores4)
{
    int t = blockIdx.x * 256 + threadIdx.x;
    int wv = t >> 6, lane = t & 63;

    if (t < G_N) { cnt[t] = 0; fb[t] = INT_MAX; }
    if (t < A_N) assigned[t] = -1;
    if (t < (A_N * 81) / 4) out_scores4[t] = make_float4(0.f, 0.f, 0.f, 0.f);

    // logsum[a] = sum_c log_sigmoid(-s[a,c]) = -sum_c (max(s,0) + log1p(exp(-|s|)))
    const float* row = scores + (long)wv * NC;
    float acc = 0.f;
    for (int c = lane; c < NC; c += 64) {
        float s = row[c];
        acc -= (fmaxf(s, 0.f) + log1pf(expf(-fabsf(s))));
    }
    #pragma unroll
    for (int off = 32; off > 0; off >>= 1) acc += __shfl_down(acc, off);
    if (lane == 0) logsum[wv] = acc;
}

// Anchor-parallel sparse emission, gt-chunked for occupancy:
// grid (132 anchor-blocks, 8 gt-chunks) x 256 threads.
// inside == in_gt exactly (RADIUS=2.5 makes the center test redundant).
__global__ __launch_bounds__(256) void k_pairs(
    const float* __restrict__ scores, const float* __restrict__ pred_b,
    const float* __restrict__ anchors, const int* __restrict__ gt_labels,
    const float* __restrict__ gt_b, const float* __restrict__ logsum,
    unsigned long long* __restrict__ bucket, int* __restrict__ cnt)
{
    __shared__ float4 gbox[GCHUNK];
    __shared__ int glab[GCHUNK];
    int tid = threadIdx.x;
    int gc = blockIdx.y;
    if (tid < GCHUNK) {
        gbox[tid] = reinterpret_cast<const float4*>(gt_b)[gc * GCHUNK + tid];
        glab[tid] = gt_labels[gc * GCHUNK + tid];
    }
    __syncthreads();

    int a = blockIdx.x * 256 + tid;
    if (a >= A_N) return;

    float4 pb = reinterpret_cast<const float4*>(pred_b)[a];
    float2 ap = reinterpret_cast<const float2*>(anchors)[a];
    float area_p = (pb.z - pb.x) * (pb.w - pb.y);
    float ls = logsum[a];

    #pragma unroll 4
    for (int g = 0; g < GCHUNK; g++) {
        float4 gb = gbox[g];   // LDS broadcast
        bool in_gt = (ap.x >= gb.x) & (ap.x <= gb.z) & (ap.y >= gb.y) & (ap.y <= gb.w);
        if (!in_gt) continue;

        float ltx = fmaxf(gb.x, pb.x), lty = fmaxf(gb.y, pb.y);
        float rbx = fminf(gb.z, pb.z), rby = fminf(gb.w, pb.w);
        float w = fmaxf(rbx - ltx, 0.f), h = fmaxf(rby - lty, 0.f);
        float overlap = w * h;
        if (!(overlap > 0.f)) continue;   // inside & iou==0 -> +inf cost, never selected

        int gg = gc * GCHUNK + g;
        float area_g = (gb.z - gb.x) * (gb.w - gb.y);
        float uni = area_g + area_p - overlap + 1e-6f;
        float iou = overlap / uni;
        float s = scores[(long)a * NC + glab[g]];
        // log_sigmoid(s)-log_sigmoid(-s) == s (shared log1p term cancels)
        float cost = (-s - ls) + 3.0f * (-logf(iou));
        unsigned long long key = ((unsigned long long)ford(cost) << 32) | (unsigned int)a;

        int slot = atomicAdd(&cnt[gg], 1);
        if (slot < CAP) bucket[(size_t)gg * CAP + slot] = key;
    }
}

// Segmented fallback for cnt==0 gts: lowest-index anchor whose pred box overlaps
// the gt (all iou>0 anchors tie at cost exactly 1e10 -> index tiebreak; iou==0 is
// +inf). grid (FBSEG, G_N); blocks with cnt!=0 exit immediately.
__global__ __launch_bounds__(256) void k_fb(
    const int* __restrict__ cnt, const float* __restrict__ pred_b,
    const float* __restrict__ gt_b, int* __restrict__ fb)
{
    int g = blockIdx.y;
    if (cnt[g] != 0) return;
    int tid = threadIdx.x;
    int wid = tid >> 6, lane = tid & 63;
    __shared__ int smin[4];

    float4 gb = reinterpret_cast<const float4*>(gt_b)[g];
    int a0 = blockIdx.x * FBSEG_LEN;
    int best = INT_MAX;
    for (int a = a0 + tid; a < a0 + FBSEG_LEN; a += 256) {
        float4 pb = reinterpret_cast<const float4*>(pred_b)[a];
        float w = fminf(gb.z, pb.z) - fmaxf(gb.x, pb.x);
        float h = fminf(gb.w, pb.w) - fmaxf(gb.y, pb.y);
        if (w > 0.f && h > 0.f && a < best) best = a;
    }
    #pragma unroll
    for (int off = 32; off; off >>= 1) best = min(best, __shfl_down(best, off));
    if (lane == 0) smin[wid] = best;
    __syncthreads();
    if (tid == 0) {
        int m = min(min(smin[0], smin[1]), min(smin[2], smin[3]));
        if (m != INT_MAX) atomicMin(&fb[g], m);
    }
}

// One block per gt: select min(cnt,10) smallest keys (exact, order-independent),
// scatter atomicMax into assigned. cnt==0: winner precomputed in fb[g].
__global__ __launch_bounds__(256) void k_select(
    const unsigned long long* __restrict__ bucket, const int* __restrict__ cnt_arr,
    const int* __restrict__ fb, int* __restrict__ assigned)
{
    int g = blockIdx.x, tid = threadIdx.x;
    int wid = tid >> 6, lane = tid & 63;
    __shared__ unsigned long long swin[4];
    __shared__ unsigned long long sel[KK];

    int cnt = cnt_arr[g];

    if (cnt == 0) {
        if (tid == 0) {
            int m = fb[g];
            if (m == INT_MAX) m = 0;   // no overlapping anchor at all -> index 0
            atomicMax(&assigned[m], g);
        }
        return;
    }

    int k = cnt < KK ? cnt : KK;
    int nreal = cnt < CAP ? cnt : CAP;
    const unsigned long long* bk = bucket + (size_t)g * CAP;
    unsigned long long kv[NLOAD];
    #pragma unroll
    for (int i = 0; i < NLOAD; i++) {
        int idx = tid + i * 256;
        kv[i] = (idx < nreal) ? bk[idx] : ~0ull;
    }

    for (int it = 0; it < k; it++) {
        unsigned long long m = kv[0];
        #pragma unroll
        for (int i = 1; i < NLOAD; i++) m = umin64(m, kv[i]);
        #pragma unroll
        for (int off = 32; off; off >>= 1) m = umin64(m, __shfl_down(m, off));
        if (lane == 0) swin[wid] = m;
        __syncthreads();
        if (tid == 0)
            sel[it] = umin64(umin64(swin[0], swin[1]), umin64(swin[2], swin[3]));
        __syncthreads();
        unsigned long long win = sel[it];
        #pragma unroll
        for (int i = 0; i < NLOAD; i++) if (kv[i] == win) kv[i] = ~0ull;  // unique key
    }

    if (tid < k) atomicMax(&assigned[(int)(sel[tid] & 0xffffffffu)], g);
}

__global__ void k_out(const int* __restrict__ assigned, const int* __restrict__ gt_labels,
                      const float* __restrict__ gt_b, const float* __restrict__ pred_b,
                      float* __restrict__ out_labels, float* __restrict__ out_bbox,
                      float* __restrict__ out_scores) {
    int a = blockIdx.x * blockDim.x + threadIdx.x;
    if (a >= A_N) return;
    int g = assigned[a];
    bool pos = g >= 0;
    int label = NC;
    float4 ob = make_float4(0.f, 0.f, 0.f, 0.f);
    float val = 0.f;
    if (pos) {
        label = gt_labels[g];
        float x1 = gt_b[g*4+0], y1 = gt_b[g*4+1], x2 = gt_b[g*4+2], y2 = gt_b[g*4+3];
        ob = make_float4(x1, y1, x2, y2);
        float4 pb = reinterpret_cast<const float4*>(pred_b)[a];
        float ltx = fmaxf(x1, pb.x), lty = fmaxf(y1, pb.y);
        float rbx = fminf(x2, pb.z), rby = fminf(y2, pb.w);
        float w = fmaxf(rbx-ltx, 0.f), h = fmaxf(rby-lty, 0.f);
        float overlap = w*h;
        float area_g = (x2-x1)*(y2-y1);
        float area_p = (pb.z-pb.x)*(pb.w-pb.y);
        float uni = area_g + area_p - overlap + 1e-6f;
        val = overlap/uni;
    }
    out_labels[a] = (float)label;
    reinterpret_cast<float4*>(out_bbox)[a] = ob;
    out_scores[(long)a*(NC+1) + label] = val;
}

extern "C" void kernel_launch(void* const* d_in, const int* in_sizes, int n_in,
                              void* d_out, int out_size, void* d_ws, size_t ws_size,
                              hipStream_t stream) {
    const float* pred_scores   = (const float*)d_in[0];
    const float* pred_bboxes   = (const float*)d_in[1];
    const float* anchor_points = (const float*)d_in[2];
    const int*   gt_labels     = (const int*)d_in[3];
    const float* gt_bboxes     = (const float*)d_in[4];

    char* ws = (char*)d_ws;
    unsigned long long* bucket = (unsigned long long*)ws;              // G*CAP u64 (8B-aligned first)
    size_t off = (size_t)G_N * CAP * 8;                                // 4 MiB
    int*   assigned = (int*)(ws + off);      off += (size_t)A_N * 4;
    int*   cnt      = (int*)(ws + off);      off += (size_t)G_N * 4;
    int*   fb       = (int*)(ws + off);      off += (size_t)G_N * 4;
    float* logsum   = (float*)(ws + off);

    float* out_labels = (float*)d_out;          // A
    float* out_bbox   = out_labels + A_N;       // A*4
    float* out_scores = out_bbox + 4*A_N;       // A*81 (offset 672000 B, 16B-aligned)

    k_init<<<A_N / 4, 256, 0, stream>>>(pred_scores, logsum, cnt, fb, assigned,
                                        (float4*)out_scores);
    dim3 pg((A_N + 255) / 256, NCHUNK);
    k_pairs<<<pg, 256, 0, stream>>>(pred_scores, pred_bboxes, anchor_points,
                                    gt_labels, gt_bboxes, logsum, bucket, cnt);
    dim3 fg(FBSEG, G_N);
    k_fb<<<fg, 256, 0, stream>>>(cnt, pred_bboxes, gt_bboxes, fb);
    k_select<<<G_N, 256, 0, stream>>>(bucket, cnt, fb, assigned);
    k_out<<<(A_N + 255) / 256, 256, 0, stream>>>(assigned, gt_labels, gt_bboxes,
                                                 pred_bboxes, out_labels, out_bbox, out_scores);
}